// Round 12
// baseline (1192.523 us; speedup 1.0000x reference)
//
#include <hip/hip_runtime.h>
#include <hip/hip_bf16.h>
#include <cstdint>

typedef __attribute__((ext_vector_type(8))) short short8_t;
typedef __attribute__((ext_vector_type(4))) float f32x4;
typedef __attribute__((ext_vector_type(16))) float f32x16;

#define LOG2E 1.4426950408889634f

__device__ __forceinline__ ushort f2bf(float f){
  union { float f; uint32_t i; } x; x.f = f;
  uint32_t r = x.i + 0x7FFFu + ((x.i >> 16) & 1u);
  return (ushort)(r >> 16);
}
__device__ __forceinline__ float fexp2(float x){
  float r; asm("v_exp_f32 %0, %1" : "=v"(r) : "v"(x)); return r;
}
__device__ __forceinline__ uint32_t cvtpk_bf16(float lo, float hi){
  uint32_t r;
  asm("v_cvt_pk_bf16_f32 %0, %1, %2" : "=v"(r) : "v"(lo), "v"(hi));
  return r;
}
__device__ __forceinline__ void pl32swap(uint32_t &a, uint32_t &b){
  asm volatile("v_permlane32_swap_b32 %0, %1" : "+v"(a), "+v"(b));
}
union PF { uint32_t u[4]; short8_t v; };

// ---------------- fused f32 -> bf16 conversion: x + 4 weights ----------------
__global__ __launch_bounds__(256) void cvt_all_kernel(const float* __restrict__ x,
                                                      const float* __restrict__ Wq,
                                                      const float* __restrict__ Wk,
                                                      const float* __restrict__ Wv,
                                                      const float* __restrict__ Wo,
                                                      ushort* __restrict__ xb,
                                                      ushort* __restrict__ wqb,
                                                      ushort* __restrict__ wkb,
                                                      ushort* __restrict__ wvb,
                                                      ushort* __restrict__ wob){
  int bid = blockIdx.x;
  const float* s; ushort* d; int i;
  if (bid < 4096){ s = x; d = xb; i = bid * 256 + threadIdx.x; }
  else {
    int sel = (bid - 4096) >> 10;
    s = sel == 0 ? Wq : sel == 1 ? Wk : sel == 2 ? Wv : Wo;
    d = sel == 0 ? wqb : sel == 1 ? wkb : sel == 2 ? wvb : wob;
    i = ((bid - 4096) & 1023) * 256 + threadIdx.x;
  }
  float4 v = ((const float4*)s)[i];
  ushort4 o;
  o.x = f2bf(v.x); o.y = f2bf(v.y); o.z = f2bf(v.z); o.w = f2bf(v.w);
  ((ushort4*)d)[i] = o;
}

// ---------------- scalar prep ----------------
// sc[0..7]=LOG2E*cos_scale[h] (Q scale), sc[8..15]=unused, sc[16..23]=2*delta_gain[h],
// sc[24]=lambda_full
__global__ void prep_kernel(const float* __restrict__ lq1, const float* __restrict__ lk1,
                            const float* __restrict__ lq2, const float* __restrict__ lk2,
                            const float* __restrict__ dgain, const float* __restrict__ chd,
                            const float* __restrict__ rawp, float* __restrict__ sc){
  int lane = threadIdx.x;  // 64 threads
  float p1 = lq1[lane] * lk1[lane];
  float p2 = lq2[lane] * lk2[lane];
  #pragma unroll
  for (int o = 1; o < 64; o <<= 1){
    p1 += __shfl_xor(p1, o, 64);
    p2 += __shfl_xor(p2, o, 64);
  }
  if (lane == 0) sc[24] = expf(p1) - expf(p2) + 0.5f;
  if (lane < 8){
    float m = 0.f;
    for (int i = 0; i < 8; i++) m += chd[i];
    m *= 0.125f;
    float gs = 15.f / (1.f + expf(-rawp[0]));
    float cs = gs * (1.f + 0.5f * tanhf(chd[lane] - m));
    sc[lane]      = LOG2E * cs;          // folded into Q
    sc[8 + lane]  = LOG2E * (cs + 1.f);  // (unused; kept for layout)
    sc[16 + lane] = 2.f * dgain[lane];   // tanh gain
  }
}

// ---------------- fused QKV GEMM: grid (32, 8, 3), block 256 ----------------
__global__ __launch_bounds__(256) void gemm_qkv(const ushort* __restrict__ A,
                                                const ushort* __restrict__ wqb,
                                                const ushort* __restrict__ wkb,
                                                const ushort* __restrict__ wvb,
                                                ushort* __restrict__ Qs,
                                                ushort* __restrict__ Kn,
                                                ushort* __restrict__ Vt,
                                                const float* __restrict__ sc){
  constexpr int N = 1024, K = 1024;
  __shared__ ushort As[128*32];
  __shared__ ushort Bs[128*32];
  const int z = blockIdx.z;
  const ushort* Bm = z == 0 ? wqb : (z == 1 ? wkb : wvb);
  const int t = threadIdx.x;
  const int lane = t & 63;
  const int w = t >> 6;
  const int wr = w >> 1, wc = w & 1;
  const long Ar0 = (long)blockIdx.x * 128;
  const long Br0 = (long)blockIdx.y * 128;
  const int r15 = lane & 15;
  const int kb = (lane >> 4) * 8;

  f32x4 acc[4][4];
  #pragma unroll
  for (int m = 0; m < 4; m++)
    #pragma unroll
    for (int n = 0; n < 4; n++) acc[m][n] = (f32x4){0.f, 0.f, 0.f, 0.f};

  for (int k0 = 0; k0 < K; k0 += 32){
    __syncthreads();
    #pragma unroll
    for (int r = 0; r < 2; r++){
      int li = r * 256 + t;
      int row = li >> 2;
      int col = (li & 3) * 8;
      __builtin_amdgcn_global_load_lds(
        (const __attribute__((address_space(1))) uint32_t*)(A + (Ar0 + row) * K + k0 + col),
        (__attribute__((address_space(3))) uint32_t*)(As + li * 8), 16, 0, 0);
      __builtin_amdgcn_global_load_lds(
        (const __attribute__((address_space(1))) uint32_t*)(Bm + (Br0 + row) * K + k0 + col),
        (__attribute__((address_space(3))) uint32_t*)(Bs + li * 8), 16, 0, 0);
    }
    __syncthreads();
    short8_t af[4], bfv[4];
    #pragma unroll
    for (int m = 0; m < 4; m++) af[m]  = *(const short8_t*)(As + (wr*64 + m*16 + r15)*32 + kb);
    #pragma unroll
    for (int n = 0; n < 4; n++) bfv[n] = *(const short8_t*)(Bs + (wc*64 + n*16 + r15)*32 + kb);
    #pragma unroll
    for (int m = 0; m < 4; m++)
      #pragma unroll
      for (int n = 0; n < 4; n++)
        acc[m][n] = __builtin_amdgcn_mfma_f32_16x16x32_bf16(af[m], bfv[n], acc[m][n], 0, 0, 0);
  }

  const int fr = (lane >> 4) * 4;
  if (z == 2){
    #pragma unroll
    for (int m = 0; m < 4; m++){
      #pragma unroll
      for (int n = 0; n < 4; n++){
        long row0 = Ar0 + wr*64 + m*16 + fr;
        long col  = Br0 + wc*64 + n*16 + r15;
        int bidx = (int)(row0 >> 11);
        int tok  = (int)(row0 & 2047);
        int hh   = (int)(col >> 7);
        int dd   = (int)(col & 127);
        ushort4 pk;
        pk.x = f2bf(acc[m][n][0]); pk.y = f2bf(acc[m][n][1]);
        pk.z = f2bf(acc[m][n][2]); pk.w = f2bf(acc[m][n][3]);
        *(ushort4*)(Vt + ((long)((bidx*8 + hh)*128 + dd))*2048 + tok) = pk;
      }
    }
  } else {
    ushort* dst = (z == 0) ? Qs : Kn;
    const float qsc = (z == 0) ? sc[Br0 >> 7] : 1.f;
    #pragma unroll
    for (int m = 0; m < 4; m++){
      float ss[4] = {0.f, 0.f, 0.f, 0.f};
      #pragma unroll
      for (int n = 0; n < 4; n++)
        #pragma unroll
        for (int r = 0; r < 4; r++) ss[r] = fmaf(acc[m][n][r], acc[m][n][r], ss[r]);
      #pragma unroll
      for (int r = 0; r < 4; r++){
        ss[r] += __shfl_xor(ss[r], 1, 16);
        ss[r] += __shfl_xor(ss[r], 2, 16);
        ss[r] += __shfl_xor(ss[r], 4, 16);
        ss[r] += __shfl_xor(ss[r], 8, 16);
        ss[r] = qsc / fmaxf(sqrtf(ss[r]), 1e-6f);
      }
      long row0 = Ar0 + wr*64 + m*16 + fr;
      #pragma unroll
      for (int n = 0; n < 4; n++){
        long col = Br0 + wc*64 + n*16 + r15;
        #pragma unroll
        for (int r = 0; r < 4; r++)
          dst[(row0 + r) * N + col] = f2bf(acc[m][n][r] * ss[r]);
      }
    }
  }
}

// ---------------- output GEMM, 64x128 tiles: grid (64, 8), 2 blocks/CU ----------------
__global__ __launch_bounds__(256) void gemm_o64(const ushort* __restrict__ A,
                                                const ushort* __restrict__ Bm,
                                                float* __restrict__ Cout,
                                                const float* __restrict__ bias){
  constexpr int N = 1024, K = 1024;
  __shared__ ushort As[64*32];
  __shared__ ushort Bs[128*32];
  const int t = threadIdx.x;
  const int lane = t & 63;
  const int w = t >> 6;
  const int wr = w >> 1, wc = w & 1;
  const long Ar0 = (long)blockIdx.x * 64;
  const long Br0 = (long)blockIdx.y * 128;
  const int r15 = lane & 15;
  const int kb = (lane >> 4) * 8;

  f32x4 acc[2][4];
  #pragma unroll
  for (int m = 0; m < 2; m++)
    #pragma unroll
    for (int n = 0; n < 4; n++) acc[m][n] = (f32x4){0.f, 0.f, 0.f, 0.f};

  for (int k0 = 0; k0 < K; k0 += 32){
    __syncthreads();
    #pragma unroll
    for (int r = 0; r < 3; r++){
      int li = r * 256 + t;
      if (li < 256){
        int row = li >> 2;
        int col = (li & 3) * 8;
        __builtin_amdgcn_global_load_lds(
          (const __attribute__((address_space(1))) uint32_t*)(A + (Ar0 + row) * K + k0 + col),
          (__attribute__((address_space(3))) uint32_t*)(As + li * 8), 16, 0, 0);
      } else {
        int bi = li - 256;
        int row = bi >> 2;
        int col = (bi & 3) * 8;
        __builtin_amdgcn_global_load_lds(
          (const __attribute__((address_space(1))) uint32_t*)(Bm + (Br0 + row) * K + k0 + col),
          (__attribute__((address_space(3))) uint32_t*)(Bs + bi * 8), 16, 0, 0);
      }
    }
    __syncthreads();
    short8_t af[2], bfv[4];
    #pragma unroll
    for (int m = 0; m < 2; m++) af[m]  = *(const short8_t*)(As + (wr*32 + m*16 + r15)*32 + kb);
    #pragma unroll
    for (int n = 0; n < 4; n++) bfv[n] = *(const short8_t*)(Bs + (wc*64 + n*16 + r15)*32 + kb);
    #pragma unroll
    for (int m = 0; m < 2; m++)
      #pragma unroll
      for (int n = 0; n < 4; n++)
        acc[m][n] = __builtin_amdgcn_mfma_f32_16x16x32_bf16(af[m], bfv[n], acc[m][n], 0, 0, 0);
  }

  const int fr = (lane >> 4) * 4;
  #pragma unroll
  for (int m = 0; m < 2; m++){
    #pragma unroll
    for (int n = 0; n < 4; n++){
      long row0 = Ar0 + wr*32 + m*16 + fr;
      long col  = Br0 + wc*64 + n*16 + r15;
      float bsv = bias[col];
      #pragma unroll
      for (int r = 0; r < 4; r++)
        Cout[(row0 + r) * N + col] = acc[m][n][r] + bsv;
    }
  }
}

// ---------------- MFMA differential attention: 8 waves = 2 qt x 4 kp, shared tiles ----
// grid (2048/64, 16); block 512. wave w: qt = w>>2, kp = w&3; kp covers keys
// [kp*512, kp*512+512) in 16 iters of 32 keys. 4-way tree merge through LDS.
__global__ __launch_bounds__(512, 4) void attn8_kernel(
    const ushort* __restrict__ Qs, const ushort* __restrict__ Kn,
    const ushort* __restrict__ Vt, ushort* __restrict__ Yb,
    const float* __restrict__ sc, const float* __restrict__ subw){
  __shared__ ushort KV[4][8192];              // [kp]: K tile (4096) + V tile (4096) ushorts
  __shared__ float Zb[2][2][2][64];           // [qt][comp][slot][lane]
  const int t = threadIdx.x;                  // 0..511
  const int w = t >> 6;
  const int l = t & 63;
  const int lo5 = l & 31;
  const int hi = l >> 5;
  const int qt = w >> 2;
  const int kp = w & 3;
  const int bh = blockIdx.y;
  const int b = bh >> 3, h = bh & 7;
  const int q0 = blockIdx.x * 64 + qt * 32;
  const float dgh2 = sc[16 + h];   // 2*delta_gain
  const float lam  = sc[24];
  const int f2 = (lo5 & 3) ^ ((lo5 >> 2) & 3);   // V read swizzle (per-lane)

  short8_t qf[8];
  {
    const ushort* qp = Qs + (long)(b*2048 + q0 + lo5) * 1024 + h*128 + hi*8;
    #pragma unroll
    for (int c = 0; c < 2; c++)
      #pragma unroll
      for (int kc = 0; kc < 4; kc++)
        qf[c*4 + kc] = *(const short8_t*)(qp + c*64 + kc*16);
  }

  f32x16 y1a[4], y2a[4];
  #pragma unroll
  for (int nt = 0; nt < 4; nt++)
    #pragma unroll
    for (int i = 0; i < 16; i++){ y1a[nt][i] = 0.f; y2a[nt][i] = 0.f; }
  float Z1 = 0.f, Z2 = 0.f;

  const long kslice = (long)b * 2048 * 1024 + h * 128;
  const long vslice = (long)(b*8 + h) * 128 * 2048;

  // per-thread static staging offsets (t covers one K chunk + one V chunk per kp tile)
  const int skey = t >> 4;                                   // 0..31
  const int koff = skey * 1024 + (((t & 15) ^ (skey & 15)) * 8);
  const int sdim = t >> 2;                                   // 0..127
  const int sfv  = (sdim & 3) ^ ((sdim >> 2) & 3);
  const int voff = sdim * 2048 + (((t & 3) ^ sfv) * 8);

  for (int it = 0; it < 16; it++){
    __syncthreads();                          // prior compute done, tiles reusable
    const int it32 = it * 32;
    #pragma unroll
    for (int kpi = 0; kpi < 4; kpi++){
      const ushort* bk = Kn + kslice + (long)(kpi*512 + it32) * 1024;
      __builtin_amdgcn_global_load_lds(
        (const __attribute__((address_space(1))) uint32_t*)(bk + koff),
        (__attribute__((address_space(3))) uint32_t*)(&KV[kpi][0] + t * 8), 16, 0, 0);
      const ushort* bv = Vt + vslice + (kpi*512 + it32);
      __builtin_amdgcn_global_load_lds(
        (const __attribute__((address_space(1))) uint32_t*)(bv + voff),
        (__attribute__((address_space(3))) uint32_t*)(&KV[kpi][4096] + t * 8), 16, 0, 0);
    }
    __syncthreads();                          // drains loads
    const ushort* Ks = &KV[kp][0];
    const ushort* Vs = &KV[kp][4096];

    // ---- QK^T (swapped: A=K rows, B=Q^T), 32 keys
    const int key = lo5;
    const int krow = key * 128;
    const int ksw = key & 15;
    f32x16 s1, s2;
    #pragma unroll
    for (int i = 0; i < 16; i++){ s1[i] = 0.f; s2[i] = 0.f; }
    #pragma unroll
    for (int kc = 0; kc < 4; kc++){
      short8_t kf = *(const short8_t*)(Ks + krow + (((kc*2 + hi) ^ ksw) * 8));
      s1 = __builtin_amdgcn_mfma_f32_32x32x16_bf16(kf, qf[kc], s1, 0, 0, 0);
    }
    #pragma unroll
    for (int kc = 0; kc < 4; kc++){
      short8_t kf = *(const short8_t*)(Ks + krow + (((8 + kc*2 + hi) ^ ksw) * 8));
      s2 = __builtin_amdgcn_mfma_f32_32x32x16_bf16(kf, qf[4 + kc], s2, 0, 0, 0);
    }

    // ---- softmax (log2 domain, unshifted) + pack to PV A-fragments
    uint32_t pa1[8], pa2[8];
    #pragma unroll
    for (int ks = 0; ks < 2; ks++){
      #pragma unroll
      for (int u = 0; u < 2; u++){
        const int rr = 8*ks + 2*u;
        float e1[4], e2[4];
        #pragma unroll
        for (int g4 = 0; g4 < 4; g4++){
          const int r = rr + (g4 >> 1)*4 + (g4 & 1);
          float a = s1[r], c = s2[r];
          float e  = fexp2(dgh2 * (a - c));
          float rc = __builtin_amdgcn_rcpf(e + 1.f);
          float gl = fmaf(-2.f * LOG2E, rc, LOG2E);
          float p1 = fexp2(a + gl);
          float p2 = fexp2(c - gl);
          Z1 += p1; Z2 += p2;
          e1[g4] = p1; e2[g4] = p2;
        }
        uint32_t a1 = cvtpk_bf16(e1[0], e1[1]), b1 = cvtpk_bf16(e1[2], e1[3]);
        uint32_t a2 = cvtpk_bf16(e2[0], e2[1]), b2 = cvtpk_bf16(e2[2], e2[3]);
        pl32swap(a1, b1);
        pl32swap(a2, b2);
        pa1[ks*4 + u] = a1; pa1[ks*4 + 2 + u] = b1;
        pa2[ks*4 + u] = a2; pa2[ks*4 + 2 + u] = b2;
      }
    }

    // ---- PV
    #pragma unroll
    for (int ks = 0; ks < 2; ks++){
      PF pf1, pf2;
      #pragma unroll
      for (int i = 0; i < 4; i++){ pf1.u[i] = pa1[ks*4 + i]; pf2.u[i] = pa2[ks*4 + i]; }
      const int ck = ks*2 + hi;
      #pragma unroll
      for (int nt = 0; nt < 4; nt++){
        const int dim = nt*32 + lo5;
        short8_t vf = *(const short8_t*)(Vs + dim*32 + ((ck ^ f2) * 8));
        y1a[nt] = __builtin_amdgcn_mfma_f32_32x32x16_bf16(pf1.v, vf, y1a[nt], 0, 0, 0);
        y2a[nt] = __builtin_amdgcn_mfma_f32_32x32x16_bf16(pf2.v, vf, y2a[nt], 0, 0, 0);
      }
    }
  }

  // combine hi/lo key-halves within each wave
  Z1 += __shfl_xor(Z1, 32, 64);
  Z2 += __shfl_xor(Z2, 32, 64);

  // ---- 4-way tree merge through LDS (flat elementwise; region = (qt*2+s)*4096) ----
  __syncthreads();                            // B1: all compute done, KV reusable
  float* Mb = (float*)(&KV[0][0]);            // 16384 floats = 64 KB
  const int s = kp >> 1;
  const int Rb = (qt*2 + s) * 4096;
  // Phase 1: y1, pairwise (kp1->kp0, kp3->kp2); Z piggybacks
  if (kp & 1){
    #pragma unroll
    for (int nt = 0; nt < 4; nt++)
      #pragma unroll
      for (int i = 0; i < 16; i++)
        Mb[Rb + (nt*16 + i)*64 + l] = y1a[nt][i];
    Zb[qt][0][s][l] = Z1; Zb[qt][1][s][l] = Z2;
  }
  __syncthreads();                            // B2
  if (!(kp & 1)){
    #pragma unroll
    for (int nt = 0; nt < 4; nt++)
      #pragma unroll
      for (int i = 0; i < 16; i++)
        y1a[nt][i] += Mb[Rb + (nt*16 + i)*64 + l];
    Z1 += Zb[qt][0][s][l]; Z2 += Zb[qt][1][s][l];
  }
  __syncthreads();                            // B3
  // Phase 2: y2, pairwise
  if (kp & 1){
    #pragma unroll
    for (int nt = 0; nt < 4; nt++)
      #pragma unroll
      for (int i = 0; i < 16; i++)
        Mb[Rb + (nt*16 + i)*64 + l] = y2a[nt][i];
  }
  __syncthreads();                            // B4
  if (!(kp & 1)){
    #pragma unroll
    for (int nt = 0; nt < 4; nt++)
      #pragma unroll
      for (int i = 0; i < 16; i++)
        y2a[nt][i] += Mb[Rb + (nt*16 + i)*64 + l];
  }
  __syncthreads();                            // B5
  // Phase 3: y1, kp2 -> kp0; Z piggybacks
  const int Rb0 = qt * 4096;
  if (kp == 2){
    #pragma unroll
    for (int nt = 0; nt < 4; nt++)
      #pragma unroll
      for (int i = 0; i < 16; i++)
        Mb[Rb0 + (nt*16 + i)*64 + l] = y1a[nt][i];
    Zb[qt][0][0][l] = Z1; Zb[qt][1][0][l] = Z2;
  }
  __syncthreads();                            // B6
  if (kp == 0){
    #pragma unroll
    for (int nt = 0; nt < 4; nt++)
      #pragma unroll
      for (int i = 0; i < 16; i++)
        y1a[nt][i] += Mb[Rb0 + (nt*16 + i)*64 + l];
    Z1 += Zb[qt][0][0][l]; Z2 += Zb[qt][1][0][l];
  }
  __syncthreads();                            // B7
  // Phase 4: y2, kp2 -> kp0
  if (kp == 2){
    #pragma unroll
    for (int nt = 0; nt < 4; nt++)
      #pragma unroll
      for (int i = 0; i < 16; i++)
        Mb[Rb0 + (nt*16 + i)*64 + l] = y2a[nt][i];
  }
  __syncthreads();                            // B8 (last barrier)
  if (kp != 0) return;
  #pragma unroll
  for (int nt = 0; nt < 4; nt++)
    #pragma unroll
    for (int i = 0; i < 16; i++)
      y2a[nt][i] += Mb[Rb0 + (nt*16 + i)*64 + l];

  // ---- epilogue: per-row RMS + subln + 0.5, write bf16 (kp==0 waves only)
  #pragma unroll
  for (int r = 0; r < 16; r++){
    const int qr = (r & 3) + 8*(r >> 2) + 4*hi;
    float z1r = __shfl(Z1, (l & 32) | qr, 64);
    float z2r = __shfl(Z2, (l & 32) | qr, 64);
    float inv1 = 1.f / z1r;
    float inv2 = lam / z2r;
    float yv[4]; float ssq = 0.f;
    #pragma unroll
    for (int nt = 0; nt < 4; nt++){
      yv[nt] = y1a[nt][r]*inv1 - y2a[nt][r]*inv2;
      ssq = fmaf(yv[nt], yv[nt], ssq);
    }
    ssq += __shfl_xor(ssq, 1, 64);
    ssq += __shfl_xor(ssq, 2, 64);
    ssq += __shfl_xor(ssq, 4, 64);
    ssq += __shfl_xor(ssq, 8, 64);
    ssq += __shfl_xor(ssq, 16, 64);
    float rms = rsqrtf(ssq * (1.f / 128.f) + 1e-5f);
    const long tok = (long)b*2048 + q0 + qr;
    ushort* op = Yb + tok*1024 + h*128;
    #pragma unroll
    for (int nt = 0; nt < 4; nt++){
      const int dim = nt*32 + lo5;
      op[dim] = f2bf(yv[nt] * rms * subw[dim] * 0.5f);
    }
  }
}

extern "C" void kernel_launch(void* const* d_in, const int* in_sizes, int n_in,
                              void* d_out, int out_size, void* d_ws, size_t ws_size,
                              hipStream_t stream) {
  const float* x   = (const float*)d_in[0];
  const float* Wq  = (const float*)d_in[1];
  const float* Wk  = (const float*)d_in[2];
  const float* Wv  = (const float*)d_in[3];
  const float* Wo  = (const float*)d_in[4];
  const float* bo  = (const float*)d_in[5];
  const float* lq1 = (const float*)d_in[6];
  const float* lk1 = (const float*)d_in[7];
  const float* lq2 = (const float*)d_in[8];
  const float* lk2 = (const float*)d_in[9];
  const float* dg  = (const float*)d_in[10];
  const float* chd = (const float*)d_in[11];
  const float* raw = (const float*)d_in[12];
  const float* subw= (const float*)d_in[13];
  float* out = (float*)d_out;

  char* ws = (char*)d_ws;
  const size_t MB = 1024 * 1024;
  ushort* xb  = (ushort*)(ws);                  // 8 MB
  ushort* wqb = (ushort*)(ws + 8 * MB);         // 2 MB each
  ushort* wkb = wqb + 1024 * 1024;
  ushort* wvb = wkb + 1024 * 1024;
  ushort* wob = wvb + 1024 * 1024;
  ushort* Qs  = (ushort*)(ws + 16 * MB);        // 8 MB
  ushort* Kn  = Qs + 4 * 1024 * 1024;           // 8 MB
  ushort* Vt  = Kn + 4 * 1024 * 1024;           // 8 MB
  ushort* Yb  = Vt + 4 * 1024 * 1024;           // 8 MB
  float*  sc  = (float*)(Yb + 4 * 1024 * 1024); // 128 B

  cvt_all_kernel<<<8192, 256, 0, stream>>>(x, Wq, Wk, Wv, Wo, xb, wqb, wkb, wvb, wob);
  prep_kernel<<<1, 64, 0, stream>>>(lq1, lk1, lq2, lk2, dg, chd, raw, sc);

  gemm_qkv<<<dim3(32, 8, 3), 256, 0, stream>>>(xb, wqb, wkb, wvb, Qs, Kn, Vt, sc);

  attn8_kernel<<<dim3(32, 16), 512, 0, stream>>>(Qs, Kn, Vt, Yb, sc, subw);

  gemm_o64<<<dim3(64, 8), 256, 0, stream>>>(Yb, wob, out, bo);
}

// Round 14
// 162.378 us; speedup vs baseline: 7.3441x; 7.3441x over previous
//
#include <hip/hip_runtime.h>
#include <hip/hip_bf16.h>
#include <cstdint>

typedef __attribute__((ext_vector_type(8))) short short8_t;
typedef __attribute__((ext_vector_type(4))) float f32x4;
typedef __attribute__((ext_vector_type(16))) float f32x16;

#define LOG2E 1.4426950408889634f

__device__ __forceinline__ ushort f2bf(float f){
  union { float f; uint32_t i; } x; x.f = f;
  uint32_t r = x.i + 0x7FFFu + ((x.i >> 16) & 1u);
  return (ushort)(r >> 16);
}
__device__ __forceinline__ float fexp2(float x){
  float r; asm("v_exp_f32 %0, %1" : "=v"(r) : "v"(x)); return r;
}
__device__ __forceinline__ uint32_t cvtpk_bf16(float lo, float hi){
  uint32_t r;
  asm("v_cvt_pk_bf16_f32 %0, %1, %2" : "=v"(r) : "v"(lo), "v"(hi));
  return r;
}
__device__ __forceinline__ void pl32swap(uint32_t &a, uint32_t &b){
  asm volatile("v_permlane32_swap_b32 %0, %1" : "+v"(a), "+v"(b));
}
union PF { uint32_t u[4]; short8_t v; };

// ---------------- fused f32 -> bf16 conversion: x + 4 weights ----------------
__global__ __launch_bounds__(256) void cvt_all_kernel(const float* __restrict__ x,
                                                      const float* __restrict__ Wq,
                                                      const float* __restrict__ Wk,
                                                      const float* __restrict__ Wv,
                                                      const float* __restrict__ Wo,
                                                      ushort* __restrict__ xb,
                                                      ushort* __restrict__ wqb,
                                                      ushort* __restrict__ wkb,
                                                      ushort* __restrict__ wvb,
                                                      ushort* __restrict__ wob){
  int bid = blockIdx.x;
  const float* s; ushort* d; int i;
  if (bid < 4096){ s = x; d = xb; i = bid * 256 + threadIdx.x; }
  else {
    int sel = (bid - 4096) >> 10;
    s = sel == 0 ? Wq : sel == 1 ? Wk : sel == 2 ? Wv : Wo;
    d = sel == 0 ? wqb : sel == 1 ? wkb : sel == 2 ? wvb : wob;
    i = ((bid - 4096) & 1023) * 256 + threadIdx.x;
  }
  float4 v = ((const float4*)s)[i];
  ushort4 o;
  o.x = f2bf(v.x); o.y = f2bf(v.y); o.z = f2bf(v.z); o.w = f2bf(v.w);
  ((ushort4*)d)[i] = o;
}

// ---------------- scalar prep ----------------
// sc[0..7]=LOG2E*cos_scale[h] (Q scale), sc[8..15]=unused, sc[16..23]=2*delta_gain[h],
// sc[24]=lambda_full
__global__ void prep_kernel(const float* __restrict__ lq1, const float* __restrict__ lk1,
                            const float* __restrict__ lq2, const float* __restrict__ lk2,
                            const float* __restrict__ dgain, const float* __restrict__ chd,
                            const float* __restrict__ rawp, float* __restrict__ sc){
  int lane = threadIdx.x;  // 64 threads
  float p1 = lq1[lane] * lk1[lane];
  float p2 = lq2[lane] * lk2[lane];
  #pragma unroll
  for (int o = 1; o < 64; o <<= 1){
    p1 += __shfl_xor(p1, o, 64);
    p2 += __shfl_xor(p2, o, 64);
  }
  if (lane == 0) sc[24] = expf(p1) - expf(p2) + 0.5f;
  if (lane < 8){
    float m = 0.f;
    for (int i = 0; i < 8; i++) m += chd[i];
    m *= 0.125f;
    float gs = 15.f / (1.f + expf(-rawp[0]));
    float cs = gs * (1.f + 0.5f * tanhf(chd[lane] - m));
    sc[lane]      = LOG2E * cs;          // folded into Q
    sc[8 + lane]  = LOG2E * (cs + 1.f);  // (unused; kept for layout)
    sc[16 + lane] = 2.f * dgain[lane];   // tanh gain
  }
}

// ---------------- fused QKV GEMM: grid (32, 8, 3), block 256 ----------------
__global__ __launch_bounds__(256) void gemm_qkv(const ushort* __restrict__ A,
                                                const ushort* __restrict__ wqb,
                                                const ushort* __restrict__ wkb,
                                                const ushort* __restrict__ wvb,
                                                ushort* __restrict__ Qs,
                                                ushort* __restrict__ Kn,
                                                ushort* __restrict__ Vt,
                                                const float* __restrict__ sc){
  constexpr int N = 1024, K = 1024;
  __shared__ ushort As[128*32];
  __shared__ ushort Bs[128*32];
  const int z = blockIdx.z;
  const ushort* Bm = z == 0 ? wqb : (z == 1 ? wkb : wvb);
  const int t = threadIdx.x;
  const int lane = t & 63;
  const int w = t >> 6;
  const int wr = w >> 1, wc = w & 1;
  const long Ar0 = (long)blockIdx.x * 128;
  const long Br0 = (long)blockIdx.y * 128;
  const int r15 = lane & 15;
  const int kb = (lane >> 4) * 8;

  f32x4 acc[4][4];
  #pragma unroll
  for (int m = 0; m < 4; m++)
    #pragma unroll
    for (int n = 0; n < 4; n++) acc[m][n] = (f32x4){0.f, 0.f, 0.f, 0.f};

  for (int k0 = 0; k0 < K; k0 += 32){
    __syncthreads();
    #pragma unroll
    for (int r = 0; r < 2; r++){
      int li = r * 256 + t;
      int row = li >> 2;
      int col = (li & 3) * 8;
      __builtin_amdgcn_global_load_lds(
        (const __attribute__((address_space(1))) uint32_t*)(A + (Ar0 + row) * K + k0 + col),
        (__attribute__((address_space(3))) uint32_t*)(As + li * 8), 16, 0, 0);
      __builtin_amdgcn_global_load_lds(
        (const __attribute__((address_space(1))) uint32_t*)(Bm + (Br0 + row) * K + k0 + col),
        (__attribute__((address_space(3))) uint32_t*)(Bs + li * 8), 16, 0, 0);
    }
    __syncthreads();
    short8_t af[4], bfv[4];
    #pragma unroll
    for (int m = 0; m < 4; m++) af[m]  = *(const short8_t*)(As + (wr*64 + m*16 + r15)*32 + kb);
    #pragma unroll
    for (int n = 0; n < 4; n++) bfv[n] = *(const short8_t*)(Bs + (wc*64 + n*16 + r15)*32 + kb);
    #pragma unroll
    for (int m = 0; m < 4; m++)
      #pragma unroll
      for (int n = 0; n < 4; n++)
        acc[m][n] = __builtin_amdgcn_mfma_f32_16x16x32_bf16(af[m], bfv[n], acc[m][n], 0, 0, 0);
  }

  const int fr = (lane >> 4) * 4;
  if (z == 2){
    #pragma unroll
    for (int m = 0; m < 4; m++){
      #pragma unroll
      for (int n = 0; n < 4; n++){
        long row0 = Ar0 + wr*64 + m*16 + fr;
        long col  = Br0 + wc*64 + n*16 + r15;
        int bidx = (int)(row0 >> 11);
        int tok  = (int)(row0 & 2047);
        int hh   = (int)(col >> 7);
        int dd   = (int)(col & 127);
        ushort4 pk;
        pk.x = f2bf(acc[m][n][0]); pk.y = f2bf(acc[m][n][1]);
        pk.z = f2bf(acc[m][n][2]); pk.w = f2bf(acc[m][n][3]);
        *(ushort4*)(Vt + ((long)((bidx*8 + hh)*128 + dd))*2048 + tok) = pk;
      }
    }
  } else {
    ushort* dst = (z == 0) ? Qs : Kn;
    const float qsc = (z == 0) ? sc[Br0 >> 7] : 1.f;
    #pragma unroll
    for (int m = 0; m < 4; m++){
      float ss[4] = {0.f, 0.f, 0.f, 0.f};
      #pragma unroll
      for (int n = 0; n < 4; n++)
        #pragma unroll
        for (int r = 0; r < 4; r++) ss[r] = fmaf(acc[m][n][r], acc[m][n][r], ss[r]);
      #pragma unroll
      for (int r = 0; r < 4; r++){
        ss[r] += __shfl_xor(ss[r], 1, 16);
        ss[r] += __shfl_xor(ss[r], 2, 16);
        ss[r] += __shfl_xor(ss[r], 4, 16);
        ss[r] += __shfl_xor(ss[r], 8, 16);
        ss[r] = qsc / fmaxf(sqrtf(ss[r]), 1e-6f);
      }
      long row0 = Ar0 + wr*64 + m*16 + fr;
      #pragma unroll
      for (int n = 0; n < 4; n++){
        long col = Br0 + wc*64 + n*16 + r15;
        #pragma unroll
        for (int r = 0; r < 4; r++)
          dst[(row0 + r) * N + col] = f2bf(acc[m][n][r] * ss[r]);
      }
    }
  }
}

// ---------------- output GEMM, 64x128 tiles: grid (64, 8), 2 blocks/CU ----------------
__global__ __launch_bounds__(256) void gemm_o64(const ushort* __restrict__ A,
                                                const ushort* __restrict__ Bm,
                                                float* __restrict__ Cout,
                                                const float* __restrict__ bias){
  constexpr int N = 1024, K = 1024;
  __shared__ ushort As[64*32];
  __shared__ ushort Bs[128*32];
  const int t = threadIdx.x;
  const int lane = t & 63;
  const int w = t >> 6;
  const int wr = w >> 1, wc = w & 1;
  const long Ar0 = (long)blockIdx.x * 64;
  const long Br0 = (long)blockIdx.y * 128;
  const int r15 = lane & 15;
  const int kb = (lane >> 4) * 8;

  f32x4 acc[2][4];
  #pragma unroll
  for (int m = 0; m < 2; m++)
    #pragma unroll
    for (int n = 0; n < 4; n++) acc[m][n] = (f32x4){0.f, 0.f, 0.f, 0.f};

  for (int k0 = 0; k0 < K; k0 += 32){
    __syncthreads();
    #pragma unroll
    for (int r = 0; r < 3; r++){
      int li = r * 256 + t;
      if (li < 256){
        int row = li >> 2;
        int col = (li & 3) * 8;
        __builtin_amdgcn_global_load_lds(
          (const __attribute__((address_space(1))) uint32_t*)(A + (Ar0 + row) * K + k0 + col),
          (__attribute__((address_space(3))) uint32_t*)(As + li * 8), 16, 0, 0);
      } else {
        int bi = li - 256;
        int row = bi >> 2;
        int col = (bi & 3) * 8;
        __builtin_amdgcn_global_load_lds(
          (const __attribute__((address_space(1))) uint32_t*)(Bm + (Br0 + row) * K + k0 + col),
          (__attribute__((address_space(3))) uint32_t*)(Bs + bi * 8), 16, 0, 0);
      }
    }
    __syncthreads();
    short8_t af[2], bfv[4];
    #pragma unroll
    for (int m = 0; m < 2; m++) af[m]  = *(const short8_t*)(As + (wr*32 + m*16 + r15)*32 + kb);
    #pragma unroll
    for (int n = 0; n < 4; n++) bfv[n] = *(const short8_t*)(Bs + (wc*64 + n*16 + r15)*32 + kb);
    #pragma unroll
    for (int m = 0; m < 2; m++)
      #pragma unroll
      for (int n = 0; n < 4; n++)
        acc[m][n] = __builtin_amdgcn_mfma_f32_16x16x32_bf16(af[m], bfv[n], acc[m][n], 0, 0, 0);
  }

  const int fr = (lane >> 4) * 4;
  #pragma unroll
  for (int m = 0; m < 2; m++){
    #pragma unroll
    for (int n = 0; n < 4; n++){
      long row0 = Ar0 + wr*32 + m*16 + fr;
      long col  = Br0 + wc*64 + n*16 + r15;
      float bsv = bias[col];
      #pragma unroll
      for (int r = 0; r < 4; r++)
        Cout[(row0 + r) * N + col] = acc[m][n][r] + bsv;
    }
  }
}

// ---------------- MFMA differential attention: K-split x2 + double-buffered 32-key tiles ----
// grid (2048/64, 16); block 256. wave w: qt = w>>1, kp = w&1. (R9-verified)
__global__ __launch_bounds__(256, 2) void attn6_kernel(
    const ushort* __restrict__ Qs, const ushort* __restrict__ Kn,
    const ushort* __restrict__ Vt, ushort* __restrict__ Yb,
    const float* __restrict__ sc, const float* __restrict__ subw){
  __shared__ ushort KV[2][2][8192];           // [kp][buf]: K tile + V tile (16 KB per pair)
  __shared__ float Zb[2][2][64];              // [qt][comp][lane]
  const int t = threadIdx.x;
  const int w = t >> 6;
  const int l = t & 63;
  const int lo5 = l & 31;
  const int hi = l >> 5;
  const int qt = w >> 1;
  const int kp = w & 1;
  const int bh = blockIdx.y;
  const int b = bh >> 3, h = bh & 7;
  const int q0 = blockIdx.x * 64 + qt * 32;
  const float dgh2 = sc[16 + h];   // 2*delta_gain
  const float lam  = sc[24];
  const int f2 = (lo5 & 3) ^ ((lo5 >> 2) & 3);   // V read swizzle (per-lane)

  short8_t qf[8];
  {
    const ushort* qp = Qs + (long)(b*2048 + q0 + lo5) * 1024 + h*128 + hi*8;
    #pragma unroll
    for (int c = 0; c < 2; c++)
      #pragma unroll
      for (int kc = 0; kc < 4; kc++)
        qf[c*4 + kc] = *(const short8_t*)(qp + c*64 + kc*16);
  }

  f32x16 y1a[4], y2a[4];
  #pragma unroll
  for (int nt = 0; nt < 4; nt++)
    #pragma unroll
    for (int i = 0; i < 16; i++){ y1a[nt][i] = 0.f; y2a[nt][i] = 0.f; }
  float Z1 = 0.f, Z2 = 0.f;

  const long kslice = (long)b * 2048 * 1024 + h * 128;
  const long vslice = (long)(b*8 + h) * 128 * 2048;

  int koff[2], kdst[2], voff[2], vdst[2];
  #pragma unroll
  for (int r = 0; r < 2; r++){
    int c = r * 256 + t;
    int key = c >> 4, ci = c & 15;
    kdst[r] = c * 8;
    koff[r] = key * 1024 + ((ci ^ (key & 15)) * 8);
    int dim = c >> 2, ci2 = c & 3;
    int fv = (dim & 3) ^ ((dim >> 2) & 3);
    vdst[r] = 4096 + c * 8;
    voff[r] = dim * 2048 + ((ci2 ^ fv) * 8);
  }

  auto stage = [&](int tileKp, int buf, int ktAbs){
    const ushort* bk = Kn + kslice + (long)ktAbs * 1024;
    const ushort* bv = Vt + vslice + ktAbs;
    ushort* dst = &KV[tileKp][buf][0];
    #pragma unroll
    for (int r = 0; r < 2; r++){
      __builtin_amdgcn_global_load_lds(
        (const __attribute__((address_space(1))) uint32_t*)(bk + koff[r]),
        (__attribute__((address_space(3))) uint32_t*)(dst + kdst[r]), 16, 0, 0);
      __builtin_amdgcn_global_load_lds(
        (const __attribute__((address_space(1))) uint32_t*)(bv + voff[r]),
        (__attribute__((address_space(3))) uint32_t*)(dst + vdst[r]), 16, 0, 0);
    }
  };

  stage(0, 0, 0);
  stage(1, 0, 1024);
  int buf = 0;
  for (int it = 0; it < 32; it++, buf ^= 1){
    __syncthreads();   // drains buf's loads; prior compute on buf^1 done
    if (it + 1 < 32){
      stage(0, buf ^ 1, (it + 1) * 32);
      stage(1, buf ^ 1, 1024 + (it + 1) * 32);
    }
    const ushort* Ks = &KV[kp][buf][0];
    const ushort* Vs = &KV[kp][buf][4096];

    // ---- QK^T (swapped: A=K rows, B=Q^T), 32 keys
    const int key = lo5;
    const int krow = key * 128;
    const int ksw = key & 15;
    f32x16 s1, s2;
    #pragma unroll
    for (int i = 0; i < 16; i++){ s1[i] = 0.f; s2[i] = 0.f; }
    #pragma unroll
    for (int kc = 0; kc < 4; kc++){
      short8_t kf = *(const short8_t*)(Ks + krow + (((kc*2 + hi) ^ ksw) * 8));
      s1 = __builtin_amdgcn_mfma_f32_32x32x16_bf16(kf, qf[kc], s1, 0, 0, 0);
    }
    #pragma unroll
    for (int kc = 0; kc < 4; kc++){
      short8_t kf = *(const short8_t*)(Ks + krow + (((8 + kc*2 + hi) ^ ksw) * 8));
      s2 = __builtin_amdgcn_mfma_f32_32x32x16_bf16(kf, qf[4 + kc], s2, 0, 0, 0);
    }

    // ---- softmax (log2 domain, unshifted) + pack to PV A-fragments
    uint32_t pa1[8], pa2[8];
    #pragma unroll
    for (int ks = 0; ks < 2; ks++){
      #pragma unroll
      for (int u = 0; u < 2; u++){
        const int rr = 8*ks + 2*u;
        float e1[4], e2[4];
        #pragma unroll
        for (int g4 = 0; g4 < 4; g4++){
          const int r = rr + (g4 >> 1)*4 + (g4 & 1);   // rr, rr+1, rr+4, rr+5
          float a = s1[r], c = s2[r];
          float e  = fexp2(dgh2 * (a - c));
          float rc = __builtin_amdgcn_rcpf(e + 1.f);
          float gl = fmaf(-2.f * LOG2E, rc, LOG2E);    // LOG2E * tanh
          float p1 = fexp2(a + gl);                    // shift dropped (cancels in p/Z)
          float p2 = fexp2(c - gl);
          Z1 += p1; Z2 += p2;
          e1[g4] = p1; e2[g4] = p2;
        }
        uint32_t a1 = cvtpk_bf16(e1[0], e1[1]), b1 = cvtpk_bf16(e1[2], e1[3]);
        uint32_t a2 = cvtpk_bf16(e2[0], e2[1]), b2 = cvtpk_bf16(e2[2], e2[3]);
        pl32swap(a1, b1);
        pl32swap(a2, b2);
        pa1[ks*4 + u] = a1; pa1[ks*4 + 2 + u] = b1;
        pa2[ks*4 + u] = a2; pa2[ks*4 + 2 + u] = b2;
      }
    }

    // ---- PV: y[q][dim] += P(32q x 16k) @ V(16k x 32d), 4 dim-tiles
    #pragma unroll
    for (int ks = 0; ks < 2; ks++){
      PF pf1, pf2;
      #pragma unroll
      for (int i = 0; i < 4; i++){ pf1.u[i] = pa1[ks*4 + i]; pf2.u[i] = pa2[ks*4 + i]; }
      const int ck = ks*2 + hi;                        // 0..3 (V rows are 32 keys = 4 chunks)
      #pragma unroll
      for (int nt = 0; nt < 4; nt++){
        const int dim = nt*32 + lo5;
        short8_t vf = *(const short8_t*)(Vs + dim*32 + ((ck ^ f2) * 8));
        y1a[nt] = __builtin_amdgcn_mfma_f32_32x32x16_bf16(pf1.v, vf, y1a[nt], 0, 0, 0);
        y2a[nt] = __builtin_amdgcn_mfma_f32_32x32x16_bf16(pf2.v, vf, y2a[nt], 0, 0, 0);
      }
    }
  }

  // combine hi/lo key-halves within each wave
  Z1 += __shfl_xor(Z1, 32, 64);
  Z2 += __shfl_xor(Z2, 32, 64);

  // ---- K-partition merge through LDS (elementwise, flat layout) ----
  __syncthreads();                       // all compute done; KV safe to reuse
  float* Mb = (float*)(&KV[0][0][0]);    // exactly 16384 floats
  if (kp == 1){
    #pragma unroll
    for (int nt = 0; nt < 4; nt++)
      #pragma unroll
      for (int i = 0; i < 16; i++){
        Mb[(((qt*2 + 0)*4 + nt)*16 + i)*64 + l] = y1a[nt][i];
        Mb[(((qt*2 + 1)*4 + nt)*16 + i)*64 + l] = y2a[nt][i];
      }
    Zb[qt][0][l] = Z1; Zb[qt][1][l] = Z2;
  }
  __syncthreads();
  if (kp == 1) return;

  #pragma unroll
  for (int nt = 0; nt < 4; nt++)
    #pragma unroll
    for (int i = 0; i < 16; i++){
      y1a[nt][i] += Mb[(((qt*2 + 0)*4 + nt)*16 + i)*64 + l];
      y2a[nt][i] += Mb[(((qt*2 + 1)*4 + nt)*16 + i)*64 + l];
    }
  Z1 += Zb[qt][0][l];
  Z2 += Zb[qt][1][l];

  // ---- epilogue: per-row RMS + subln + 0.5, write bf16
  #pragma unroll
  for (int r = 0; r < 16; r++){
    const int qr = (r & 3) + 8*(r >> 2) + 4*hi;
    float z1r = __shfl(Z1, (l & 32) | qr, 64);
    float z2r = __shfl(Z2, (l & 32) | qr, 64);
    float inv1 = 1.f / z1r;
    float inv2 = lam / z2r;
    float yv[4]; float ssq = 0.f;
    #pragma unroll
    for (int nt = 0; nt < 4; nt++){
      yv[nt] = y1a[nt][r]*inv1 - y2a[nt][r]*inv2;
      ssq = fmaf(yv[nt], yv[nt], ssq);
    }
    ssq += __shfl_xor(ssq, 1, 64);
    ssq += __shfl_xor(ssq, 2, 64);
    ssq += __shfl_xor(ssq, 4, 64);
    ssq += __shfl_xor(ssq, 8, 64);
    ssq += __shfl_xor(ssq, 16, 64);
    float rms = rsqrtf(ssq * (1.f / 128.f) + 1e-5f);
    const long tok = (long)b*2048 + q0 + qr;
    ushort* op = Yb + tok*1024 + h*128;
    #pragma unroll
    for (int nt = 0; nt < 4; nt++){
      const int dim = nt*32 + lo5;
      op[dim] = f2bf(yv[nt] * rms * subw[dim] * 0.5f);
    }
  }
}

extern "C" void kernel_launch(void* const* d_in, const int* in_sizes, int n_in,
                              void* d_out, int out_size, void* d_ws, size_t ws_size,
                              hipStream_t stream) {
  const float* x   = (const float*)d_in[0];
  const float* Wq  = (const float*)d_in[1];
  const float* Wk  = (const float*)d_in[2];
  const float* Wv  = (const float*)d_in[3];
  const float* Wo  = (const float*)d_in[4];
  const float* bo  = (const float*)d_in[5];
  const float* lq1 = (const float*)d_in[6];
  const float* lk1 = (const float*)d_in[7];
  const float* lq2 = (const float*)d_in[8];
  const float* lk2 = (const float*)d_in[9];
  const float* dg  = (const float*)d_in[10];
  const float* chd = (const float*)d_in[11];
  const float* raw = (const float*)d_in[12];
  const float* subw= (const float*)d_in[13];
  float* out = (float*)d_out;

  char* ws = (char*)d_ws;
  const size_t MB = 1024 * 1024;
  ushort* xb  = (ushort*)(ws);                  // 8 MB
  ushort* wqb = (ushort*)(ws + 8 * MB);         // 2 MB each
  ushort* wkb = wqb + 1024 * 1024;
  ushort* wvb = wkb + 1024 * 1024;
  ushort* wob = wvb + 1024 * 1024;
  ushort* Qs  = (ushort*)(ws + 16 * MB);        // 8 MB
  ushort* Kn  = Qs + 4 * 1024 * 1024;           // 8 MB
  ushort* Vt  = Kn + 4 * 1024 * 1024;           // 8 MB
  ushort* Yb  = Vt + 4 * 1024 * 1024;           // 8 MB
  float*  sc  = (float*)(Yb + 4 * 1024 * 1024); // 128 B

  cvt_all_kernel<<<8192, 256, 0, stream>>>(x, Wq, Wk, Wv, Wo, xb, wqb, wkb, wvb, wob);
  prep_kernel<<<1, 64, 0, stream>>>(lq1, lk1, lq2, lk2, dg, chd, raw, sc);

  gemm_qkv<<<dim3(32, 8, 3), 256, 0, stream>>>(xb, wqb, wkb, wvb, Qs, Kn, Vt, sc);

  attn6_kernel<<<dim3(32, 16), 256, 0, stream>>>(Qs, Kn, Vt, Yb, sc, subw);

  gemm_o64<<<dim3(64, 8), 256, 0, stream>>>(Yb, wob, out, bo);
}

// Round 15
// 161.657 us; speedup vs baseline: 7.3769x; 1.0045x over previous
//
#include <hip/hip_runtime.h>
#include <hip/hip_bf16.h>
#include <cstdint>

typedef __attribute__((ext_vector_type(8))) short short8_t;
typedef __attribute__((ext_vector_type(4))) float f32x4;
typedef __attribute__((ext_vector_type(16))) float f32x16;

#define LOG2E 1.4426950408889634f

__device__ __forceinline__ ushort f2bf(float f){
  union { float f; uint32_t i; } x; x.f = f;
  uint32_t r = x.i + 0x7FFFu + ((x.i >> 16) & 1u);
  return (ushort)(r >> 16);
}
__device__ __forceinline__ float fexp2(float x){
  float r; asm("v_exp_f32 %0, %1" : "=v"(r) : "v"(x)); return r;
}
__device__ __forceinline__ uint32_t cvtpk_bf16(float lo, float hi){
  uint32_t r;
  asm("v_cvt_pk_bf16_f32 %0, %1, %2" : "=v"(r) : "v"(lo), "v"(hi));
  return r;
}
__device__ __forceinline__ void pl32swap(uint32_t &a, uint32_t &b){
  asm volatile("v_permlane32_swap_b32 %0, %1" : "+v"(a), "+v"(b));
}
union PF { uint32_t u[4]; short8_t v; };

// ---------------- fused f32 -> bf16 conversion: x + 4 weights ----------------
__global__ __launch_bounds__(256) void cvt_all_kernel(const float* __restrict__ x,
                                                      const float* __restrict__ Wq,
                                                      const float* __restrict__ Wk,
                                                      const float* __restrict__ Wv,
                                                      const float* __restrict__ Wo,
                                                      ushort* __restrict__ xb,
                                                      ushort* __restrict__ wqb,
                                                      ushort* __restrict__ wkb,
                                                      ushort* __restrict__ wvb,
                                                      ushort* __restrict__ wob){
  int bid = blockIdx.x;
  const float* s; ushort* d; int i;
  if (bid < 4096){ s = x; d = xb; i = bid * 256 + threadIdx.x; }
  else {
    int sel = (bid - 4096) >> 10;
    s = sel == 0 ? Wq : sel == 1 ? Wk : sel == 2 ? Wv : Wo;
    d = sel == 0 ? wqb : sel == 1 ? wkb : sel == 2 ? wvb : wob;
    i = ((bid - 4096) & 1023) * 256 + threadIdx.x;
  }
  float4 v = ((const float4*)s)[i];
  ushort4 o;
  o.x = f2bf(v.x); o.y = f2bf(v.y); o.z = f2bf(v.z); o.w = f2bf(v.w);
  ((ushort4*)d)[i] = o;
}

// ---------------- scalar prep ----------------
// sc[0..7]=LOG2E*cos_scale[h] (Q scale), sc[8..15]=unused, sc[16..23]=2*delta_gain[h],
// sc[24]=lambda_full
__global__ void prep_kernel(const float* __restrict__ lq1, const float* __restrict__ lk1,
                            const float* __restrict__ lq2, const float* __restrict__ lk2,
                            const float* __restrict__ dgain, const float* __restrict__ chd,
                            const float* __restrict__ rawp, float* __restrict__ sc){
  int lane = threadIdx.x;  // 64 threads
  float p1 = lq1[lane] * lk1[lane];
  float p2 = lq2[lane] * lk2[lane];
  #pragma unroll
  for (int o = 1; o < 64; o <<= 1){
    p1 += __shfl_xor(p1, o, 64);
    p2 += __shfl_xor(p2, o, 64);
  }
  if (lane == 0) sc[24] = expf(p1) - expf(p2) + 0.5f;
  if (lane < 8){
    float m = 0.f;
    for (int i = 0; i < 8; i++) m += chd[i];
    m *= 0.125f;
    float gs = 15.f / (1.f + expf(-rawp[0]));
    float cs = gs * (1.f + 0.5f * tanhf(chd[lane] - m));
    sc[lane]      = LOG2E * cs;          // folded into Q
    sc[8 + lane]  = LOG2E * (cs + 1.f);  // (unused; kept for layout)
    sc[16 + lane] = 2.f * dgain[lane];   // tanh gain
  }
}

// ---------------- fused QKV GEMM: grid (32, 8, 3), block 256 ----------------
__global__ __launch_bounds__(256) void gemm_qkv(const ushort* __restrict__ A,
                                                const ushort* __restrict__ wqb,
                                                const ushort* __restrict__ wkb,
                                                const ushort* __restrict__ wvb,
                                                ushort* __restrict__ Qs,
                                                ushort* __restrict__ Kn,
                                                ushort* __restrict__ Vt,
                                                const float* __restrict__ sc){
  constexpr int N = 1024, K = 1024;
  __shared__ ushort As[128*32];
  __shared__ ushort Bs[128*32];
  const int z = blockIdx.z;
  const ushort* Bm = z == 0 ? wqb : (z == 1 ? wkb : wvb);
  const int t = threadIdx.x;
  const int lane = t & 63;
  const int w = t >> 6;
  const int wr = w >> 1, wc = w & 1;
  const long Ar0 = (long)blockIdx.x * 128;
  const long Br0 = (long)blockIdx.y * 128;
  const int r15 = lane & 15;
  const int kb = (lane >> 4) * 8;

  f32x4 acc[4][4];
  #pragma unroll
  for (int m = 0; m < 4; m++)
    #pragma unroll
    for (int n = 0; n < 4; n++) acc[m][n] = (f32x4){0.f, 0.f, 0.f, 0.f};

  for (int k0 = 0; k0 < K; k0 += 32){
    __syncthreads();
    #pragma unroll
    for (int r = 0; r < 2; r++){
      int li = r * 256 + t;
      int row = li >> 2;
      int col = (li & 3) * 8;
      __builtin_amdgcn_global_load_lds(
        (const __attribute__((address_space(1))) uint32_t*)(A + (Ar0 + row) * K + k0 + col),
        (__attribute__((address_space(3))) uint32_t*)(As + li * 8), 16, 0, 0);
      __builtin_amdgcn_global_load_lds(
        (const __attribute__((address_space(1))) uint32_t*)(Bm + (Br0 + row) * K + k0 + col),
        (__attribute__((address_space(3))) uint32_t*)(Bs + li * 8), 16, 0, 0);
    }
    __syncthreads();
    short8_t af[4], bfv[4];
    #pragma unroll
    for (int m = 0; m < 4; m++) af[m]  = *(const short8_t*)(As + (wr*64 + m*16 + r15)*32 + kb);
    #pragma unroll
    for (int n = 0; n < 4; n++) bfv[n] = *(const short8_t*)(Bs + (wc*64 + n*16 + r15)*32 + kb);
    #pragma unroll
    for (int m = 0; m < 4; m++)
      #pragma unroll
      for (int n = 0; n < 4; n++)
        acc[m][n] = __builtin_amdgcn_mfma_f32_16x16x32_bf16(af[m], bfv[n], acc[m][n], 0, 0, 0);
  }

  const int fr = (lane >> 4) * 4;
  if (z == 2){
    #pragma unroll
    for (int m = 0; m < 4; m++){
      #pragma unroll
      for (int n = 0; n < 4; n++){
        long row0 = Ar0 + wr*64 + m*16 + fr;
        long col  = Br0 + wc*64 + n*16 + r15;
        int bidx = (int)(row0 >> 11);
        int tok  = (int)(row0 & 2047);
        int hh   = (int)(col >> 7);
        int dd   = (int)(col & 127);
        ushort4 pk;
        pk.x = f2bf(acc[m][n][0]); pk.y = f2bf(acc[m][n][1]);
        pk.z = f2bf(acc[m][n][2]); pk.w = f2bf(acc[m][n][3]);
        *(ushort4*)(Vt + ((long)((bidx*8 + hh)*128 + dd))*2048 + tok) = pk;
      }
    }
  } else {
    ushort* dst = (z == 0) ? Qs : Kn;
    const float qsc = (z == 0) ? sc[Br0 >> 7] : 1.f;
    #pragma unroll
    for (int m = 0; m < 4; m++){
      float ss[4] = {0.f, 0.f, 0.f, 0.f};
      #pragma unroll
      for (int n = 0; n < 4; n++)
        #pragma unroll
        for (int r = 0; r < 4; r++) ss[r] = fmaf(acc[m][n][r], acc[m][n][r], ss[r]);
      #pragma unroll
      for (int r = 0; r < 4; r++){
        ss[r] += __shfl_xor(ss[r], 1, 16);
        ss[r] += __shfl_xor(ss[r], 2, 16);
        ss[r] += __shfl_xor(ss[r], 4, 16);
        ss[r] += __shfl_xor(ss[r], 8, 16);
        ss[r] = qsc / fmaxf(sqrtf(ss[r]), 1e-6f);
      }
      long row0 = Ar0 + wr*64 + m*16 + fr;
      #pragma unroll
      for (int n = 0; n < 4; n++){
        long col = Br0 + wc*64 + n*16 + r15;
        #pragma unroll
        for (int r = 0; r < 4; r++)
          dst[(row0 + r) * N + col] = f2bf(acc[m][n][r] * ss[r]);
      }
    }
  }
}

// ---------------- output GEMM, 64x128 tiles: grid (64, 8), 2 blocks/CU ----------------
__global__ __launch_bounds__(256) void gemm_o64(const ushort* __restrict__ A,
                                                const ushort* __restrict__ Bm,
                                                float* __restrict__ Cout,
                                                const float* __restrict__ bias){
  constexpr int N = 1024, K = 1024;
  __shared__ ushort As[64*32];
  __shared__ ushort Bs[128*32];
  const int t = threadIdx.x;
  const int lane = t & 63;
  const int w = t >> 6;
  const int wr = w >> 1, wc = w & 1;
  const long Ar0 = (long)blockIdx.x * 64;
  const long Br0 = (long)blockIdx.y * 128;
  const int r15 = lane & 15;
  const int kb = (lane >> 4) * 8;

  f32x4 acc[2][4];
  #pragma unroll
  for (int m = 0; m < 2; m++)
    #pragma unroll
    for (int n = 0; n < 4; n++) acc[m][n] = (f32x4){0.f, 0.f, 0.f, 0.f};

  for (int k0 = 0; k0 < K; k0 += 32){
    __syncthreads();
    #pragma unroll
    for (int r = 0; r < 3; r++){
      int li = r * 256 + t;
      if (li < 256){
        int row = li >> 2;
        int col = (li & 3) * 8;
        __builtin_amdgcn_global_load_lds(
          (const __attribute__((address_space(1))) uint32_t*)(A + (Ar0 + row) * K + k0 + col),
          (__attribute__((address_space(3))) uint32_t*)(As + li * 8), 16, 0, 0);
      } else {
        int bi = li - 256;
        int row = bi >> 2;
        int col = (bi & 3) * 8;
        __builtin_amdgcn_global_load_lds(
          (const __attribute__((address_space(1))) uint32_t*)(Bm + (Br0 + row) * K + k0 + col),
          (__attribute__((address_space(3))) uint32_t*)(Bs + bi * 8), 16, 0, 0);
      }
    }
    __syncthreads();
    short8_t af[2], bfv[4];
    #pragma unroll
    for (int m = 0; m < 2; m++) af[m]  = *(const short8_t*)(As + (wr*32 + m*16 + r15)*32 + kb);
    #pragma unroll
    for (int n = 0; n < 4; n++) bfv[n] = *(const short8_t*)(Bs + (wc*64 + n*16 + r15)*32 + kb);
    #pragma unroll
    for (int m = 0; m < 2; m++)
      #pragma unroll
      for (int n = 0; n < 4; n++)
        acc[m][n] = __builtin_amdgcn_mfma_f32_16x16x32_bf16(af[m], bfv[n], acc[m][n], 0, 0, 0);
  }

  const int fr = (lane >> 4) * 4;
  #pragma unroll
  for (int m = 0; m < 2; m++){
    #pragma unroll
    for (int n = 0; n < 4; n++){
      long row0 = Ar0 + wr*32 + m*16 + fr;
      long col  = Br0 + wc*64 + n*16 + r15;
      float bsv = bias[col];
      #pragma unroll
      for (int r = 0; r < 4; r++)
        Cout[(row0 + r) * N + col] = acc[m][n][r] + bsv;
    }
  }
}

// ---------------- MFMA differential attention: K-split x2, single-buffered 32-key tiles,
// 32 KB LDS -> 4 blocks/CU. grid (2048/64, 16); block 256. wave w: qt = w>>1, kp = w&1.
__global__ __launch_bounds__(256, 2) void attn9_kernel(
    const ushort* __restrict__ Qs, const ushort* __restrict__ Kn,
    const ushort* __restrict__ Vt, ushort* __restrict__ Yb,
    const float* __restrict__ sc, const float* __restrict__ subw){
  __shared__ ushort KV[2][8192];              // [kp]: K tile (4096 ush) + V tile (4096 ush)
  __shared__ float Zb[2][2][64];              // [qt][comp][lane]
  const int t = threadIdx.x;
  const int w = t >> 6;
  const int l = t & 63;
  const int lo5 = l & 31;
  const int hi = l >> 5;
  const int qt = w >> 1;
  const int kp = w & 1;
  const int bh = blockIdx.y;
  const int b = bh >> 3, h = bh & 7;
  const int q0 = blockIdx.x * 64 + qt * 32;
  const float dgh2 = sc[16 + h];   // 2*delta_gain
  const float lam  = sc[24];
  const int f2 = (lo5 & 3) ^ ((lo5 >> 2) & 3);   // V read swizzle (per-lane)

  short8_t qf[8];
  {
    const ushort* qp = Qs + (long)(b*2048 + q0 + lo5) * 1024 + h*128 + hi*8;
    #pragma unroll
    for (int c = 0; c < 2; c++)
      #pragma unroll
      for (int kc = 0; kc < 4; kc++)
        qf[c*4 + kc] = *(const short8_t*)(qp + c*64 + kc*16);
  }

  f32x16 y1a[4], y2a[4];
  #pragma unroll
  for (int nt = 0; nt < 4; nt++)
    #pragma unroll
    for (int i = 0; i < 16; i++){ y1a[nt][i] = 0.f; y2a[nt][i] = 0.f; }
  float Z1 = 0.f, Z2 = 0.f;

  const long kslice = (long)b * 2048 * 1024 + h * 128;
  const long vslice = (long)(b*8 + h) * 128 * 2048;

  int koff[2], kdst[2], voff[2], vdst[2];
  #pragma unroll
  for (int r = 0; r < 2; r++){
    int c = r * 256 + t;
    int key = c >> 4, ci = c & 15;
    kdst[r] = c * 8;
    koff[r] = key * 1024 + ((ci ^ (key & 15)) * 8);
    int dim = c >> 2, ci2 = c & 3;
    int fv = (dim & 3) ^ ((dim >> 2) & 3);
    vdst[r] = 4096 + c * 8;
    voff[r] = dim * 2048 + ((ci2 ^ fv) * 8);
  }

  auto stage = [&](int tileKp, int ktAbs){
    const ushort* bk = Kn + kslice + (long)ktAbs * 1024;
    const ushort* bv = Vt + vslice + ktAbs;
    ushort* dst = &KV[tileKp][0];
    #pragma unroll
    for (int r = 0; r < 2; r++){
      __builtin_amdgcn_global_load_lds(
        (const __attribute__((address_space(1))) uint32_t*)(bk + koff[r]),
        (__attribute__((address_space(3))) uint32_t*)(dst + kdst[r]), 16, 0, 0);
      __builtin_amdgcn_global_load_lds(
        (const __attribute__((address_space(1))) uint32_t*)(bv + voff[r]),
        (__attribute__((address_space(3))) uint32_t*)(dst + vdst[r]), 16, 0, 0);
    }
  };

  for (int it = 0; it < 32; it++){
    __syncthreads();   // prior compute done; tiles reusable
    stage(0, it * 32);
    stage(1, 1024 + it * 32);
    __syncthreads();   // drains loads
    const ushort* Ks = &KV[kp][0];
    const ushort* Vs = &KV[kp][4096];

    // ---- QK^T (swapped: A=K rows, B=Q^T), 32 keys
    const int key = lo5;
    const int krow = key * 128;
    const int ksw = key & 15;
    f32x16 s1, s2;
    #pragma unroll
    for (int i = 0; i < 16; i++){ s1[i] = 0.f; s2[i] = 0.f; }
    #pragma unroll
    for (int kc = 0; kc < 4; kc++){
      short8_t kf = *(const short8_t*)(Ks + krow + (((kc*2 + hi) ^ ksw) * 8));
      s1 = __builtin_amdgcn_mfma_f32_32x32x16_bf16(kf, qf[kc], s1, 0, 0, 0);
    }
    #pragma unroll
    for (int kc = 0; kc < 4; kc++){
      short8_t kf = *(const short8_t*)(Ks + krow + (((8 + kc*2 + hi) ^ ksw) * 8));
      s2 = __builtin_amdgcn_mfma_f32_32x32x16_bf16(kf, qf[4 + kc], s2, 0, 0, 0);
    }

    // ---- softmax (log2 domain, unshifted) + pack to PV A-fragments
    uint32_t pa1[8], pa2[8];
    #pragma unroll
    for (int ks = 0; ks < 2; ks++){
      #pragma unroll
      for (int u = 0; u < 2; u++){
        const int rr = 8*ks + 2*u;
        float e1[4], e2[4];
        #pragma unroll
        for (int g4 = 0; g4 < 4; g4++){
          const int r = rr + (g4 >> 1)*4 + (g4 & 1);   // rr, rr+1, rr+4, rr+5
          float a = s1[r], c = s2[r];
          float e  = fexp2(dgh2 * (a - c));
          float rc = __builtin_amdgcn_rcpf(e + 1.f);
          float gl = fmaf(-2.f * LOG2E, rc, LOG2E);    // LOG2E * tanh
          float p1 = fexp2(a + gl);                    // shift dropped (cancels in p/Z)
          float p2 = fexp2(c - gl);
          Z1 += p1; Z2 += p2;
          e1[g4] = p1; e2[g4] = p2;
        }
        uint32_t a1 = cvtpk_bf16(e1[0], e1[1]), b1 = cvtpk_bf16(e1[2], e1[3]);
        uint32_t a2 = cvtpk_bf16(e2[0], e2[1]), b2 = cvtpk_bf16(e2[2], e2[3]);
        pl32swap(a1, b1);
        pl32swap(a2, b2);
        pa1[ks*4 + u] = a1; pa1[ks*4 + 2 + u] = b1;
        pa2[ks*4 + u] = a2; pa2[ks*4 + 2 + u] = b2;
      }
    }

    // ---- PV: y[q][dim] += P(32q x 16k) @ V(16k x 32d), 4 dim-tiles
    #pragma unroll
    for (int ks = 0; ks < 2; ks++){
      PF pf1, pf2;
      #pragma unroll
      for (int i = 0; i < 4; i++){ pf1.u[i] = pa1[ks*4 + i]; pf2.u[i] = pa2[ks*4 + i]; }
      const int ck = ks*2 + hi;                        // 0..3 (V rows are 32 keys = 4 chunks)
      #pragma unroll
      for (int nt = 0; nt < 4; nt++){
        const int dim = nt*32 + lo5;
        short8_t vf = *(const short8_t*)(Vs + dim*32 + ((ck ^ f2) * 8));
        y1a[nt] = __builtin_amdgcn_mfma_f32_32x32x16_bf16(pf1.v, vf, y1a[nt], 0, 0, 0);
        y2a[nt] = __builtin_amdgcn_mfma_f32_32x32x16_bf16(pf2.v, vf, y2a[nt], 0, 0, 0);
      }
    }
  }

  // combine hi/lo key-halves within each wave
  Z1 += __shfl_xor(Z1, 32, 64);
  Z2 += __shfl_xor(Z2, 32, 64);

  // ---- K-partition merge through LDS, split into y1/y2 phases (32 KB region) ----
  float* Mb = (float*)(&KV[0][0]);       // 8192 floats = 32 KB
  __syncthreads();                       // B1: all compute done; KV safe to reuse
  if (kp == 1){
    #pragma unroll
    for (int nt = 0; nt < 4; nt++)
      #pragma unroll
      for (int i = 0; i < 16; i++)
        Mb[((qt*4 + nt)*16 + i)*64 + l] = y1a[nt][i];
    Zb[qt][0][l] = Z1; Zb[qt][1][l] = Z2;
  }
  __syncthreads();                       // B2
  if (kp == 0){
    #pragma unroll
    for (int nt = 0; nt < 4; nt++)
      #pragma unroll
      for (int i = 0; i < 16; i++)
        y1a[nt][i] += Mb[((qt*4 + nt)*16 + i)*64 + l];
    Z1 += Zb[qt][0][l];
    Z2 += Zb[qt][1][l];
  }
  __syncthreads();                       // B3: kp0's y1 reads done before overwrite
  if (kp == 1){
    #pragma unroll
    for (int nt = 0; nt < 4; nt++)
      #pragma unroll
      for (int i = 0; i < 16; i++)
        Mb[((qt*4 + nt)*16 + i)*64 + l] = y2a[nt][i];
  }
  __syncthreads();                       // B4 (last barrier)
  if (kp == 1) return;
  #pragma unroll
  for (int nt = 0; nt < 4; nt++)
    #pragma unroll
    for (int i = 0; i < 16; i++)
      y2a[nt][i] += Mb[((qt*4 + nt)*16 + i)*64 + l];

  // ---- epilogue: per-row RMS + subln + 0.5, write bf16
  #pragma unroll
  for (int r = 0; r < 16; r++){
    const int qr = (r & 3) + 8*(r >> 2) + 4*hi;
    float z1r = __shfl(Z1, (l & 32) | qr, 64);
    float z2r = __shfl(Z2, (l & 32) | qr, 64);
    float inv1 = 1.f / z1r;
    float inv2 = lam / z2r;
    float yv[4]; float ssq = 0.f;
    #pragma unroll
    for (int nt = 0; nt < 4; nt++){
      yv[nt] = y1a[nt][r]*inv1 - y2a[nt][r]*inv2;
      ssq = fmaf(yv[nt], yv[nt], ssq);
    }
    ssq += __shfl_xor(ssq, 1, 64);
    ssq += __shfl_xor(ssq, 2, 64);
    ssq += __shfl_xor(ssq, 4, 64);
    ssq += __shfl_xor(ssq, 8, 64);
    ssq += __shfl_xor(ssq, 16, 64);
    float rms = rsqrtf(ssq * (1.f / 128.f) + 1e-5f);
    const long tok = (long)b*2048 + q0 + qr;
    ushort* op = Yb + tok*1024 + h*128;
    #pragma unroll
    for (int nt = 0; nt < 4; nt++){
      const int dim = nt*32 + lo5;
      op[dim] = f2bf(yv[nt] * rms * subw[dim] * 0.5f);
    }
  }
}

extern "C" void kernel_launch(void* const* d_in, const int* in_sizes, int n_in,
                              void* d_out, int out_size, void* d_ws, size_t ws_size,
                              hipStream_t stream) {
  const float* x   = (const float*)d_in[0];
  const float* Wq  = (const float*)d_in[1];
  const float* Wk  = (const float*)d_in[2];
  const float* Wv  = (const float*)d_in[3];
  const float* Wo  = (const float*)d_in[4];
  const float* bo  = (const float*)d_in[5];
  const float* lq1 = (const float*)d_in[6];
  const float* lk1 = (const float*)d_in[7];
  const float* lq2 = (const float*)d_in[8];
  const float* lk2 = (const float*)d_in[9];
  const float* dg  = (const float*)d_in[10];
  const float* chd = (const float*)d_in[11];
  const float* raw = (const float*)d_in[12];
  const float* subw= (const float*)d_in[13];
  float* out = (float*)d_out;

  char* ws = (char*)d_ws;
  const size_t MB = 1024 * 1024;
  ushort* xb  = (ushort*)(ws);                  // 8 MB
  ushort* wqb = (ushort*)(ws + 8 * MB);         // 2 MB each
  ushort* wkb = wqb + 1024 * 1024;
  ushort* wvb = wkb + 1024 * 1024;
  ushort* wob = wvb + 1024 * 1024;
  ushort* Qs  = (ushort*)(ws + 16 * MB);        // 8 MB
  ushort* Kn  = Qs + 4 * 1024 * 1024;           // 8 MB
  ushort* Vt  = Kn + 4 * 1024 * 1024;           // 8 MB
  ushort* Yb  = Vt + 4 * 1024 * 1024;           // 8 MB
  float*  sc  = (float*)(Yb + 4 * 1024 * 1024); // 128 B

  cvt_all_kernel<<<8192, 256, 0, stream>>>(x, Wq, Wk, Wv, Wo, xb, wqb, wkb, wvb, wob);
  prep_kernel<<<1, 64, 0, stream>>>(lq1, lk1, lq2, lk2, dg, chd, raw, sc);

  gemm_qkv<<<dim3(32, 8, 3), 256, 0, stream>>>(xb, wqb, wkb, wvb, Qs, Kn, Vt, sc);

  attn9_kernel<<<dim3(32, 16), 256, 0, stream>>>(Qs, Kn, Vt, Yb, sc, subw);

  gemm_o64<<<dim3(64, 8), 256, 0, stream>>>(Yb, wob, out, bo);
}